// Round 3
// baseline (254.704 us; speedup 1.0000x reference)
//
#include <hip/hip_runtime.h>

#define NV    150000
#define CIN   32
#define COUT  64
#define EPSF  1e-5f
#define NCOPY 16

#define NTHR   256
#define NTILES (NV / 16)            // 9375 exact
#define NBLKF  1024                 // 4 blocks/CU * 256 CU -> all co-resident
#define WAVES_TOT (NBLKF * 4)       // 4096 waves
#define TPW    3                    // 4096*3 = 12288 >= 9375

// ws layout (bytes):
//   [0, 110592)             ushort wfrag[27*4*64*8]  (B-fragment swizzled)
//   [110592, 118784)        float  gstats[NCOPY*128]
//   [118784, 118788)        unsigned barrier counter
#define WS_WFRAG  0
#define WS_GSTATS 110592
#define WS_BAR    (WS_GSTATS + NCOPY * 128 * 4)

typedef short  bf16x8 __attribute__((ext_vector_type(8)));
typedef float  f32x4  __attribute__((ext_vector_type(4)));

union u4bf { uint4 u; bf16x8 h; };

__device__ __forceinline__ unsigned pack_bf2(float a, float b) {
    union { float f; unsigned u; } ca, cb;
    ca.f = a; cb.f = b;
    const unsigned lo = (ca.u + 0x7FFFu + ((ca.u >> 16) & 1u)) >> 16;
    const unsigned hi = (cb.u + 0x7FFFu + ((cb.u >> 16) & 1u)) & 0xFFFF0000u;
    return lo | hi;
}

__device__ __forceinline__ u4bf pack_row(float4 f0, float4 f1) {
    u4bf r;
    r.u.x = pack_bf2(f0.x, f0.y);
    r.u.y = pack_bf2(f0.z, f0.w);
    r.u.z = pack_bf2(f1.x, f1.y);
    r.u.w = pack_bf2(f1.z, f1.w);
    return r;
}

// ---------------------------------------------------------------------------
// K0: prep — weights->B-fragment-swizzled bf16 (27 blocks) + gstats/bar zero.
// ---------------------------------------------------------------------------
__global__ __launch_bounds__(NTHR) void k_prep(
    const float* __restrict__ weight,
    char*        __restrict__ ws)
{
    const int b = blockIdx.x;
    if (b < 27) {
        const int k    = b;
        const int bb   = threadIdx.x >> 6;       // cout block 0..3
        const int lane = threadIdx.x & 63;
        const int quad = lane >> 4;
        const int lm   = lane & 15;
        const float* wsrc = weight + (long)k * CIN * COUT + (quad * 8) * COUT + bb * 16 + lm;
        float f[8];
#pragma unroll
        for (int j = 0; j < 8; ++j) f[j] = wsrc[j * COUT];
        uint4 o;
        o.x = pack_bf2(f[0], f[1]);
        o.y = pack_bf2(f[2], f[3]);
        o.z = pack_bf2(f[4], f[5]);
        o.w = pack_bf2(f[6], f[7]);
        ((uint4*)(ws + WS_WFRAG))[(k * 4 + bb) * 64 + lane] = o;
    } else {
        // zero gstats (2048 f32) + barrier counter (span covers 2304 f32)
        float* gs = (float*)(ws + WS_GSTATS);
#pragma unroll
        for (int i = 0; i < 9; ++i) gs[threadIdx.x + i * NTHR] = 0.f;
    }
}

// ---------------------------------------------------------------------------
// sidx loader: 26 taps x 16 voxels = 416 items, 7 chunks of 64
// ---------------------------------------------------------------------------
__device__ __forceinline__ void load_sidx(
    const int* __restrict__ nbr, int v0, bool have, int lane, int (&sidx)[7])
{
#pragma unroll
    for (int it = 0; it < 7; ++it) {
        const int item = lane + it * 64;
        int idx = -1;
        if (have && item < 416) {
            const int kp = item >> 4;
            const int k  = kp + (kp >= 13);
            idx = nbr[(long)k * NV + v0 + (item & 15)];
        }
        sidx[it] = idx;
    }
}

// ---------------------------------------------------------------------------
// One tile's conv into a NAMED register accumulator array (static indexing
// only inside -> guaranteed registers, rule #20).
// ---------------------------------------------------------------------------
__device__ __forceinline__ void conv_tile(
    f32x4 (&acc)[4], f32x4& ssum, f32x4& qsum,
    const float* __restrict__ feat, const uint4* __restrict__ wf,
    const int (&sidx)[7], int v0, bool have,
    int lane, int quad, int lm)
{
    if (!have) return;

    // ---- center tap MFMA (f32 feat row packed inline) ----
    {
        const float4* fp = (const float4*)(feat + (long)(v0 + lm) * CIN + quad * 8);
        const u4bf a0 = pack_row(fp[0], fp[1]);
#pragma unroll
        for (int b = 0; b < 4; ++b) {
            u4bf w; w.u = wf[(13 * 4 + b) * 64 + lane];
            acc[b] = __builtin_amdgcn_mfma_f32_16x16x32_bf16(a0.h, w.h, acc[b], 0, 0, 0);
        }
    }

    // ---- ballots -> wave-uniform 26-bit active-k mask ----
    unsigned int kmask = 0u;
#pragma unroll
    for (int it = 0; it < 7; ++it) {
        const unsigned long long m = __ballot(sidx[it] >= 0);
        kmask |= ((m & 0xFFFFull)         ? 1u : 0u) << (it * 4 + 0);
        kmask |= (((m >> 16) & 0xFFFFull) ? 1u : 0u) << (it * 4 + 1);
        kmask |= (((m >> 32) & 0xFFFFull) ? 1u : 0u) << (it * 4 + 2);
        kmask |= ((m >> 48)               ? 1u : 0u) << (it * 4 + 3);
    }

    // ---- drain: 2 active k's per iteration ----
    while (kmask) {
        const int kpA = __ffs(kmask) - 1;
        kmask &= kmask - 1u;
        int kpB = -1;
        if (kmask) { kpB = __ffs(kmask) - 1; kmask &= kmask - 1u; }
        const int kA = kpA + (kpA >= 13);
        const int kB = (kpB >= 0) ? (kpB + (kpB >= 13)) : kA;

        int rawA, rawB;
        switch (kpA >> 2) {
            case 0: rawA = sidx[0]; break; case 1: rawA = sidx[1]; break;
            case 2: rawA = sidx[2]; break; case 3: rawA = sidx[3]; break;
            case 4: rawA = sidx[4]; break; case 5: rawA = sidx[5]; break;
            default: rawA = sidx[6]; break;
        }
        const int kpB2 = (kpB >= 0) ? kpB : kpA;
        switch (kpB2 >> 2) {
            case 0: rawB = sidx[0]; break; case 1: rawB = sidx[1]; break;
            case 2: rawB = sidx[2]; break; case 3: rawB = sidx[3]; break;
            case 4: rawB = sidx[4]; break; case 5: rawB = sidx[5]; break;
            default: rawB = sidx[6]; break;
        }
        const int idxA = __shfl(rawA, ((kpA & 3) << 4) | lm);
        int idxB = __shfl(rawB, ((kpB2 & 3) << 4) | lm);
        if (kpB < 0) idxB = -1;

        const float4* fpA = (const float4*)(feat + (long)(idxA < 0 ? 0 : idxA) * CIN + quad * 8);
        const float4* fpB = (const float4*)(feat + (long)(idxB < 0 ? 0 : idxB) * CIN + quad * 8);
        u4bf aA = pack_row(fpA[0], fpA[1]);
        u4bf aB = pack_row(fpB[0], fpB[1]);
        if (idxA < 0) aA.u = make_uint4(0u, 0u, 0u, 0u);
        if (idxB < 0) aB.u = make_uint4(0u, 0u, 0u, 0u);

#pragma unroll
        for (int b = 0; b < 4; ++b) {
            u4bf wA, wB;
            wA.u = wf[(kA * 4 + b) * 64 + lane];
            wB.u = wf[(kB * 4 + b) * 64 + lane];
            acc[b] = __builtin_amdgcn_mfma_f32_16x16x32_bf16(aA.h, wA.h, acc[b], 0, 0, 0);
            acc[b] = __builtin_amdgcn_mfma_f32_16x16x32_bf16(aB.h, wB.h, acc[b], 0, 0, 0);
        }
    }

    // ---- BN partials from f32 accumulators ----
#pragma unroll
    for (int b = 0; b < 4; ++b) {
        const float r0 = acc[b][0], r1 = acc[b][1];
        const float r2 = acc[b][2], r3 = acc[b][3];
        ssum[b] += r0 + r1 + r2 + r3;
        qsum[b] += r0 * r0 + r1 * r1 + r2 * r2 + r3 * r3;
    }
}

__device__ __forceinline__ void store_tile(
    const f32x4 (&acc)[4], float* __restrict__ out, int v0, bool have,
    const float (&scv)[4], const float (&shv)[4], int quad, int lm)
{
    if (!have) return;
#pragma unroll
    for (int b = 0; b < 4; ++b) {
#pragma unroll
        for (int r = 0; r < 4; ++r) {
            out[(long)(v0 + quad * 4 + r) * COUT + b * 16 + lm] =
                fmaxf(acc[b][r] * scv[b] + shv[b], 0.f);
        }
    }
}

// ---------------------------------------------------------------------------
// K1 (persistent, software grid barrier): conv -> named register accumulators
// (3 tiles/wave), BN partials, barrier, finalize stats, affine+ReLU, f32 out.
// __launch_bounds__(256,4): compiler guarantees 4 waves/EU => 4 blocks/CU =>
// 1024 blocks co-resident with a regular (graph-capturable) launch.
// ---------------------------------------------------------------------------
__global__ __launch_bounds__(NTHR, 4) void k_fused(
    const float* __restrict__ feat,    // [NV, CIN] f32
    char*        __restrict__ ws,      // wfrag + gstats + bar
    const int*   __restrict__ nbr,     // [27, NV]
    float*       __restrict__ gstats,
    float*       __restrict__ out,     // [NV, COUT] f32
    const float* __restrict__ gamma,
    const float* __restrict__ beta)
{
    const uint4* wf = (const uint4*)(ws + WS_WFRAG);
    unsigned* bar = (unsigned*)(ws + WS_BAR);

    const int tid  = threadIdx.x;
    const int lane = tid & 63;
    const int quad = lane >> 4;
    const int lm   = lane & 15;
    const int wid  = blockIdx.x * 4 + (tid >> 6);   // wave id 0..4095

    const int w0 = wid;                 // < 4096  (< NTILES always)
    const int w1 = wid + WAVES_TOT;     // < 8192  (< NTILES always)
    const int w2 = wid + 2 * WAVES_TOT; // may exceed
    const bool h2 = (w2 < NTILES);

    f32x4 ssum = {0.f, 0.f, 0.f, 0.f};
    f32x4 qsum = {0.f, 0.f, 0.f, 0.f};
    f32x4 acc0[4], acc1[4], acc2[4];
#pragma unroll
    for (int b = 0; b < 4; ++b) {
        acc0[b] = (f32x4){0.f, 0.f, 0.f, 0.f};
        acc1[b] = (f32x4){0.f, 0.f, 0.f, 0.f};
        acc2[b] = (f32x4){0.f, 0.f, 0.f, 0.f};
    }

    int s0[7], s1[7];
    load_sidx(nbr, w0 * 16, true, lane, s0);
    load_sidx(nbr, w1 * 16, true, lane, s1);     // prefetch tile 1

    conv_tile(acc0, ssum, qsum, feat, wf, s0, w0 * 16, true, lane, quad, lm);
    load_sidx(nbr, w2 * 16, h2, lane, s0);       // prefetch tile 2
    conv_tile(acc1, ssum, qsum, feat, wf, s1, w1 * 16, true, lane, quad, lm);
    conv_tile(acc2, ssum, qsum, feat, wf, s0, w2 * 16, h2, lane, quad, lm);

    // ---- butterfly over quads ----
#pragma unroll
    for (int off = 16; off < 64; off <<= 1) {
#pragma unroll
        for (int b = 0; b < 4; ++b) {
            ssum[b] += __shfl_xor(ssum[b], off);
            qsum[b] += __shfl_xor(qsum[b], off);
        }
    }

    __shared__ float ls[4][128];
    const int wv = tid >> 6;
    if (quad == 0) {
#pragma unroll
        for (int b = 0; b < 4; ++b) {
            ls[wv][b * 16 + lm]      = ssum[b];
            ls[wv][64 + b * 16 + lm] = qsum[b];
        }
    }
    __syncthreads();
    if (tid < 128) {
        const float v = ls[0][tid] + ls[1][tid] + ls[2][tid] + ls[3][tid];
        atomicAdd(gstats + (blockIdx.x & (NCOPY - 1)) * 128 + tid, v);
    }
    __syncthreads();

    // ---- software grid barrier (all 1024 blocks co-resident) ----
    if (tid == 0) {
        __threadfence();  // release our gstats adds device-wide
        __hip_atomic_fetch_add(bar, 1u, __ATOMIC_RELEASE, __HIP_MEMORY_SCOPE_AGENT);
        while (__hip_atomic_load(bar, __ATOMIC_RELAXED, __HIP_MEMORY_SCOPE_AGENT) < (unsigned)NBLKF) {
            __builtin_amdgcn_s_sleep(8);
        }
        __threadfence();  // acquire side
    }
    __syncthreads();

    // ---- finalize stats -> scale/shift in LDS (agent-scope loads) ----
    __shared__ float sscale[COUT];
    __shared__ float sshift[COUT];
    if (tid < COUT) {
        float s = 0.f, q = 0.f;
#pragma unroll
        for (int cp = 0; cp < NCOPY; ++cp) {
            s += __hip_atomic_load(gstats + cp * 128 + tid, __ATOMIC_RELAXED, __HIP_MEMORY_SCOPE_AGENT);
            q += __hip_atomic_load(gstats + cp * 128 + 64 + tid, __ATOMIC_RELAXED, __HIP_MEMORY_SCOPE_AGENT);
        }
        const float inv_n = 1.f / (float)NV;
        const float mean = s * inv_n;
        float var = q * inv_n - mean * mean;
        var = fmaxf(var, 0.f);
        const float rstd = rsqrtf(var + EPSF);
        const float sc = gamma[tid] * rstd;
        sscale[tid] = sc;
        sshift[tid] = beta[tid] - mean * sc;
    }
    __syncthreads();

    float scv[4], shv[4];
#pragma unroll
    for (int b = 0; b < 4; ++b) {
        scv[b] = sscale[b * 16 + lm];
        shv[b] = sshift[b * 16 + lm];
    }

    // ---- affine + ReLU straight from registers -> f32 out ----
    store_tile(acc0, out, w0 * 16, true, scv, shv, quad, lm);
    store_tile(acc1, out, w1 * 16, true, scv, shv, quad, lm);
    store_tile(acc2, out, w2 * 16, h2,   scv, shv, quad, lm);
}

// ---------------------------------------------------------------------------
extern "C" void kernel_launch(void* const* d_in, const int* in_sizes, int n_in,
                              void* d_out, int out_size, void* d_ws, size_t ws_size,
                              hipStream_t stream) {
    const float* feat   = (const float*)d_in[0];
    const float* weight = (const float*)d_in[1];
    const float* gamma  = (const float*)d_in[2];
    const float* beta   = (const float*)d_in[3];
    const int*   nbr    = (const int*)d_in[4];
    float* out = (float*)d_out;

    char*  ws     = (char*)d_ws;
    float* gstats = (float*)(ws + WS_GSTATS);

    k_prep<<<28, NTHR, 0, stream>>>(weight, ws);
    k_fused<<<NBLKF, NTHR, 0, stream>>>(feat, ws, nbr, gstats, out, gamma, beta);
}

// Round 4
// 183.336 us; speedup vs baseline: 1.3893x; 1.3893x over previous
//
#include <hip/hip_runtime.h>

#define NV    150000
#define CIN   32
#define COUT  64
#define EPSF  1e-5f
#define NCOPY 16

#define NTHR   256
#define NTILES (NV / 16)            // 9375 exact
#define NBLKF  512                  // 2 blocks/CU * 256 CU -> all co-resident (proven in R2)
#define WAVES_TOT (NBLKF * 4)       // 2048 waves
#define TPW    5                    // 2048*5 = 10240 >= 9375

// ws layout (bytes):
//   [0, 110592)             ushort wfrag[27*4*64*8]  (B-fragment swizzled)
//   [110592, 118784)        float  gstats[NCOPY*128]
//   [118784, 118788)        unsigned barrier arrive counter
//   [118788, 118792)        unsigned barrier release flag
#define WS_WFRAG  0
#define WS_GSTATS 110592
#define WS_BAR    (WS_GSTATS + NCOPY * 128 * 4)

typedef short  bf16x8 __attribute__((ext_vector_type(8)));
typedef float  f32x4  __attribute__((ext_vector_type(4)));

union u4bf { uint4 u; bf16x8 h; };

__device__ __forceinline__ unsigned pack_bf2(float a, float b) {
    union { float f; unsigned u; } ca, cb;
    ca.f = a; cb.f = b;
    const unsigned lo = (ca.u + 0x7FFFu + ((ca.u >> 16) & 1u)) >> 16;
    const unsigned hi = (cb.u + 0x7FFFu + ((cb.u >> 16) & 1u)) & 0xFFFF0000u;
    return lo | hi;
}

__device__ __forceinline__ u4bf pack_row(float4 f0, float4 f1) {
    u4bf r;
    r.u.x = pack_bf2(f0.x, f0.y);
    r.u.y = pack_bf2(f0.z, f0.w);
    r.u.z = pack_bf2(f1.x, f1.y);
    r.u.w = pack_bf2(f1.z, f1.w);
    return r;
}

// ---------------------------------------------------------------------------
// K0: prep — weights->B-fragment-swizzled bf16 (27 blocks) + gstats/bar zero.
// ---------------------------------------------------------------------------
__global__ __launch_bounds__(NTHR) void k_prep(
    const float* __restrict__ weight,
    char*        __restrict__ ws)
{
    const int b = blockIdx.x;
    if (b < 27) {
        const int k    = b;
        const int bb   = threadIdx.x >> 6;       // cout block 0..3
        const int lane = threadIdx.x & 63;
        const int quad = lane >> 4;
        const int lm   = lane & 15;
        const float* wsrc = weight + (long)k * CIN * COUT + (quad * 8) * COUT + bb * 16 + lm;
        float f[8];
#pragma unroll
        for (int j = 0; j < 8; ++j) f[j] = wsrc[j * COUT];
        uint4 o;
        o.x = pack_bf2(f[0], f[1]);
        o.y = pack_bf2(f[2], f[3]);
        o.z = pack_bf2(f[4], f[5]);
        o.w = pack_bf2(f[6], f[7]);
        ((uint4*)(ws + WS_WFRAG))[(k * 4 + bb) * 64 + lane] = o;
    } else {
        // zero gstats (2048 f32) + barrier words (span covers 2304 f32)
        float* gs = (float*)(ws + WS_GSTATS);
#pragma unroll
        for (int i = 0; i < 9; ++i) gs[threadIdx.x + i * NTHR] = 0.f;
    }
}

// ---------------------------------------------------------------------------
// sidx loader: 26 taps x 16 voxels = 416 items, 7 chunks of 64
// ---------------------------------------------------------------------------
__device__ __forceinline__ void load_sidx(
    const int* __restrict__ nbr, int v0, bool have, int lane, int (&sidx)[7])
{
#pragma unroll
    for (int it = 0; it < 7; ++it) {
        const int item = lane + it * 64;
        int idx = -1;
        if (have && item < 416) {
            const int kp = item >> 4;
            const int k  = kp + (kp >= 13);
            idx = nbr[(long)k * NV + v0 + (item & 15)];
        }
        sidx[it] = idx;
    }
}

// ---------------------------------------------------------------------------
// One tile's conv into a NAMED register accumulator array (static indexing
// only -> registers, rule #20; needs generous launch-bounds cap, R3 lesson).
// ---------------------------------------------------------------------------
__device__ __forceinline__ void conv_tile(
    f32x4 (&acc)[4], f32x4& ssum, f32x4& qsum,
    const float* __restrict__ feat, const uint4* __restrict__ wf,
    const int (&sidx)[7], int v0, bool have,
    int lane, int quad, int lm)
{
    if (!have) return;

    // ---- center tap MFMA (f32 feat row packed inline) ----
    {
        const float4* fp = (const float4*)(feat + (long)(v0 + lm) * CIN + quad * 8);
        const u4bf a0 = pack_row(fp[0], fp[1]);
#pragma unroll
        for (int b = 0; b < 4; ++b) {
            u4bf w; w.u = wf[(13 * 4 + b) * 64 + lane];
            acc[b] = __builtin_amdgcn_mfma_f32_16x16x32_bf16(a0.h, w.h, acc[b], 0, 0, 0);
        }
    }

    // ---- ballots -> wave-uniform 26-bit active-k mask ----
    unsigned int kmask = 0u;
#pragma unroll
    for (int it = 0; it < 7; ++it) {
        const unsigned long long m = __ballot(sidx[it] >= 0);
        kmask |= ((m & 0xFFFFull)         ? 1u : 0u) << (it * 4 + 0);
        kmask |= (((m >> 16) & 0xFFFFull) ? 1u : 0u) << (it * 4 + 1);
        kmask |= (((m >> 32) & 0xFFFFull) ? 1u : 0u) << (it * 4 + 2);
        kmask |= ((m >> 48)               ? 1u : 0u) << (it * 4 + 3);
    }

    // ---- drain: 2 active k's per iteration ----
    while (kmask) {
        const int kpA = __ffs(kmask) - 1;
        kmask &= kmask - 1u;
        int kpB = -1;
        if (kmask) { kpB = __ffs(kmask) - 1; kmask &= kmask - 1u; }
        const int kA = kpA + (kpA >= 13);
        const int kB = (kpB >= 0) ? (kpB + (kpB >= 13)) : kA;

        int rawA, rawB;
        switch (kpA >> 2) {
            case 0: rawA = sidx[0]; break; case 1: rawA = sidx[1]; break;
            case 2: rawA = sidx[2]; break; case 3: rawA = sidx[3]; break;
            case 4: rawA = sidx[4]; break; case 5: rawA = sidx[5]; break;
            default: rawA = sidx[6]; break;
        }
        const int kpB2 = (kpB >= 0) ? kpB : kpA;
        switch (kpB2 >> 2) {
            case 0: rawB = sidx[0]; break; case 1: rawB = sidx[1]; break;
            case 2: rawB = sidx[2]; break; case 3: rawB = sidx[3]; break;
            case 4: rawB = sidx[4]; break; case 5: rawB = sidx[5]; break;
            default: rawB = sidx[6]; break;
        }
        const int idxA = __shfl(rawA, ((kpA & 3) << 4) | lm);
        int idxB = __shfl(rawB, ((kpB2 & 3) << 4) | lm);
        if (kpB < 0) idxB = -1;

        const float4* fpA = (const float4*)(feat + (long)(idxA < 0 ? 0 : idxA) * CIN + quad * 8);
        const float4* fpB = (const float4*)(feat + (long)(idxB < 0 ? 0 : idxB) * CIN + quad * 8);
        u4bf aA = pack_row(fpA[0], fpA[1]);
        u4bf aB = pack_row(fpB[0], fpB[1]);
        if (idxA < 0) aA.u = make_uint4(0u, 0u, 0u, 0u);
        if (idxB < 0) aB.u = make_uint4(0u, 0u, 0u, 0u);

#pragma unroll
        for (int b = 0; b < 4; ++b) {
            u4bf wA, wB;
            wA.u = wf[(kA * 4 + b) * 64 + lane];
            wB.u = wf[(kB * 4 + b) * 64 + lane];
            acc[b] = __builtin_amdgcn_mfma_f32_16x16x32_bf16(aA.h, wA.h, acc[b], 0, 0, 0);
            acc[b] = __builtin_amdgcn_mfma_f32_16x16x32_bf16(aB.h, wB.h, acc[b], 0, 0, 0);
        }
    }

    // ---- BN partials from f32 accumulators ----
#pragma unroll
    for (int b = 0; b < 4; ++b) {
        const float r0 = acc[b][0], r1 = acc[b][1];
        const float r2 = acc[b][2], r3 = acc[b][3];
        ssum[b] += r0 + r1 + r2 + r3;
        qsum[b] += r0 * r0 + r1 * r1 + r2 * r2 + r3 * r3;
    }
}

__device__ __forceinline__ void store_tile(
    const f32x4 (&acc)[4], float* __restrict__ out, int v0, bool have,
    const float (&scv)[4], const float (&shv)[4], int quad, int lm)
{
    if (!have) return;
#pragma unroll
    for (int b = 0; b < 4; ++b) {
#pragma unroll
        for (int r = 0; r < 4; ++r) {
            out[(long)(v0 + quad * 4 + r) * COUT + b * 16 + lm] =
                fmaxf(acc[b][r] * scv[b] + shv[b], 0.f);
        }
    }
}

// ---------------------------------------------------------------------------
// K1 (persistent): conv -> 5 named register tile-accumulators + BN partials,
// low-contention arrive/flag grid barrier, finalize stats, affine+ReLU, f32.
// __launch_bounds__(256,2): VGPR cap 256 -> no spill (R3 lesson);
// 2 blocks/CU -> 512 blocks co-resident (completion proven in R2).
// ---------------------------------------------------------------------------
__global__ __launch_bounds__(NTHR, 2) void k_fused(
    const float* __restrict__ feat,    // [NV, CIN] f32
    char*        __restrict__ ws,      // wfrag + gstats + bar/flag
    const int*   __restrict__ nbr,     // [27, NV]
    float*       __restrict__ gstats,
    float*       __restrict__ out,     // [NV, COUT] f32
    const float* __restrict__ gamma,
    const float* __restrict__ beta)
{
    const uint4* wf = (const uint4*)(ws + WS_WFRAG);
    unsigned* bar  = (unsigned*)(ws + WS_BAR);      // arrive counter
    unsigned* flag = bar + 1;                       // release flag

    const int tid  = threadIdx.x;
    const int lane = tid & 63;
    const int quad = lane >> 4;
    const int lm   = lane & 15;
    const int wid  = blockIdx.x * 4 + (tid >> 6);   // wave id 0..2047

    const int w0 = wid;                  // < 2048
    const int w1 = wid + WAVES_TOT;      // < 4096
    const int w2 = wid + 2 * WAVES_TOT;  // < 6144
    const int w3 = wid + 3 * WAVES_TOT;  // < 8192  (< NTILES always)
    const int w4 = wid + 4 * WAVES_TOT;  // may exceed 9375
    const bool h4 = (w4 < NTILES);

    f32x4 ssum = {0.f, 0.f, 0.f, 0.f};
    f32x4 qsum = {0.f, 0.f, 0.f, 0.f};
    f32x4 acc0[4], acc1[4], acc2[4], acc3[4], acc4[4];
#pragma unroll
    for (int b = 0; b < 4; ++b) {
        acc0[b] = (f32x4){0.f, 0.f, 0.f, 0.f};
        acc1[b] = (f32x4){0.f, 0.f, 0.f, 0.f};
        acc2[b] = (f32x4){0.f, 0.f, 0.f, 0.f};
        acc3[b] = (f32x4){0.f, 0.f, 0.f, 0.f};
        acc4[b] = (f32x4){0.f, 0.f, 0.f, 0.f};
    }

    // sidx double-buffer with explicit static rotation (no runtime indexing)
    int sA[7], sB[7];
    load_sidx(nbr, w0 * 16, true, lane, sA);
    load_sidx(nbr, w1 * 16, true, lane, sB);

    conv_tile(acc0, ssum, qsum, feat, wf, sA, w0 * 16, true, lane, quad, lm);
    load_sidx(nbr, w2 * 16, true, lane, sA);
    conv_tile(acc1, ssum, qsum, feat, wf, sB, w1 * 16, true, lane, quad, lm);
    load_sidx(nbr, w3 * 16, true, lane, sB);
    conv_tile(acc2, ssum, qsum, feat, wf, sA, w2 * 16, true, lane, quad, lm);
    load_sidx(nbr, w4 * 16, h4, lane, sA);
    conv_tile(acc3, ssum, qsum, feat, wf, sB, w3 * 16, true, lane, quad, lm);
    conv_tile(acc4, ssum, qsum, feat, wf, sA, w4 * 16, h4, lane, quad, lm);

    // ---- butterfly over quads ----
#pragma unroll
    for (int off = 16; off < 64; off <<= 1) {
#pragma unroll
        for (int b = 0; b < 4; ++b) {
            ssum[b] += __shfl_xor(ssum[b], off);
            qsum[b] += __shfl_xor(qsum[b], off);
        }
    }

    __shared__ float ls[4][128];
    const int wv = tid >> 6;
    if (quad == 0) {
#pragma unroll
        for (int b = 0; b < 4; ++b) {
            ls[wv][b * 16 + lm]      = ssum[b];
            ls[wv][64 + b * 16 + lm] = qsum[b];
        }
    }
    __syncthreads();
    if (tid < 128) {
        const float v = ls[0][tid] + ls[1][tid] + ls[2][tid] + ls[3][tid];
        atomicAdd(gstats + (blockIdx.x & (NCOPY - 1)) * 128 + tid, v);
    }
    __syncthreads();

    // ---- low-contention grid barrier: arrive-count + write-once flag ----
    // Only block 0 polls the hot arrive counter; 511 blocks poll the clean
    // read-shared flag line (no cross-XCD line bouncing, R3 lesson).
    if (tid == 0) {
        __threadfence();   // release our gstats adds device-wide
        __hip_atomic_fetch_add(bar, 1u, __ATOMIC_RELEASE, __HIP_MEMORY_SCOPE_AGENT);
        if (blockIdx.x == 0) {
            while (__hip_atomic_load(bar, __ATOMIC_RELAXED, __HIP_MEMORY_SCOPE_AGENT)
                   < (unsigned)NBLKF) {
                __builtin_amdgcn_s_sleep(2);
            }
            __hip_atomic_store(flag, 1u, __ATOMIC_RELEASE, __HIP_MEMORY_SCOPE_AGENT);
        } else {
            while (__hip_atomic_load(flag, __ATOMIC_RELAXED, __HIP_MEMORY_SCOPE_AGENT)
                   == 0u) {
                __builtin_amdgcn_s_sleep(8);
            }
        }
        __threadfence();   // acquire side: invalidate stale caches
    }
    __syncthreads();

    // ---- finalize stats -> scale/shift in LDS (agent-scope loads) ----
    __shared__ float sscale[COUT];
    __shared__ float sshift[COUT];
    if (tid < COUT) {
        float s = 0.f, q = 0.f;
#pragma unroll
        for (int cp = 0; cp < NCOPY; ++cp) {
            s += __hip_atomic_load(gstats + cp * 128 + tid, __ATOMIC_RELAXED, __HIP_MEMORY_SCOPE_AGENT);
            q += __hip_atomic_load(gstats + cp * 128 + 64 + tid, __ATOMIC_RELAXED, __HIP_MEMORY_SCOPE_AGENT);
        }
        const float inv_n = 1.f / (float)NV;
        const float mean = s * inv_n;
        float var = q * inv_n - mean * mean;
        var = fmaxf(var, 0.f);
        const float rstd = rsqrtf(var + EPSF);
        const float sc = gamma[tid] * rstd;
        sscale[tid] = sc;
        sshift[tid] = beta[tid] - mean * sc;
    }
    __syncthreads();

    float scv[4], shv[4];
#pragma unroll
    for (int b = 0; b < 4; ++b) {
        scv[b] = sscale[b * 16 + lm];
        shv[b] = sshift[b * 16 + lm];
    }

    // ---- affine + ReLU straight from registers -> f32 out ----
    store_tile(acc0, out, w0 * 16, true, scv, shv, quad, lm);
    store_tile(acc1, out, w1 * 16, true, scv, shv, quad, lm);
    store_tile(acc2, out, w2 * 16, true, scv, shv, quad, lm);
    store_tile(acc3, out, w3 * 16, true, scv, shv, quad, lm);
    store_tile(acc4, out, w4 * 16, h4,   scv, shv, quad, lm);
}

// ---------------------------------------------------------------------------
extern "C" void kernel_launch(void* const* d_in, const int* in_sizes, int n_in,
                              void* d_out, int out_size, void* d_ws, size_t ws_size,
                              hipStream_t stream) {
    const float* feat   = (const float*)d_in[0];
    const float* weight = (const float*)d_in[1];
    const float* gamma  = (const float*)d_in[2];
    const float* beta   = (const float*)d_in[3];
    const int*   nbr    = (const int*)d_in[4];
    float* out = (float*)d_out;

    char*  ws     = (char*)d_ws;
    float* gstats = (float*)(ws + WS_GSTATS);

    k_prep<<<28, NTHR, 0, stream>>>(weight, ws);
    k_fused<<<NBLKF, NTHR, 0, stream>>>(feat, ws, nbr, gstats, out, gamma, beta);
}

// Round 5
// 162.545 us; speedup vs baseline: 1.5670x; 1.1279x over previous
//
#include <hip/hip_runtime.h>

#define NV    150000
#define CIN   32
#define COUT  64
#define EPSF  1e-5f
#define NCOPY 16
#define NTHR  256

#define NTILES 9375                  // NV/16 exact
#define NBLKD  2344                  // dense: 4 waves/block, 1 tile/wave (9376 waves)
#define VBLK   586                   // sparse: ceil(NV/256)
#define NBLK3  1172                  // norm blocks
#define STRIDE3 (NBLK3 * NTHR)       // 300032, divisible by 16
#define CH4    (NV * COUT / 4)       // 2,400,000 float4 chunks

// ws layout (bytes):
//   [0, 221184)            f32 Wt[27][64][32]   (transposed weights, coalesced per-cout rows)
//   [221184, 225280)       uint4 w13frag[4*64]  (center-tap MFMA B-fragment, bf16)
//   [225280, 233472)       f32 gstats[NCOPY*128]
//   [233472, ...)          f32 outf[NV*COUT]    (conv result, f32: 38.4 MB)
#define WS_WT     0
#define WS_W13    221184
#define WS_GSTATS 225280
#define WS_OUTF   233472

typedef short  bf16x8 __attribute__((ext_vector_type(8)));
typedef float  f32x4  __attribute__((ext_vector_type(4)));

union u4bf { uint4 u; bf16x8 h; };

__device__ __forceinline__ unsigned pack_bf2(float a, float b) {
    union { float f; unsigned u; } ca, cb;
    ca.f = a; cb.f = b;
    const unsigned lo = (ca.u + 0x7FFFu + ((ca.u >> 16) & 1u)) >> 16;
    const unsigned hi = (cb.u + 0x7FFFu + ((cb.u >> 16) & 1u)) & 0xFFFF0000u;
    return lo | hi;
}

__device__ __forceinline__ u4bf pack_row(float4 f0, float4 f1) {
    u4bf r;
    r.u.x = pack_bf2(f0.x, f0.y);
    r.u.y = pack_bf2(f0.z, f0.w);
    r.u.z = pack_bf2(f1.x, f1.y);
    r.u.w = pack_bf2(f1.z, f1.w);
    return r;
}

// ---------------------------------------------------------------------------
// K0: prep.
//   blocks 0..26 : transpose W[k] (f32 [cin][cout]) -> Wt[k] [cout][cin]
//   block  27    : build center-tap (k=13) MFMA B-fragment (bf16, swizzled)
//   block  28    : zero gstats
// ---------------------------------------------------------------------------
__global__ __launch_bounds__(NTHR) void k_prep(
    const float* __restrict__ weight,
    char*        __restrict__ ws)
{
    const int b = blockIdx.x;
    if (b < 27) {
        const int k = b;
        float* wt = (float*)(ws + WS_WT) + (long)k * COUT * CIN;
        const float* wsrc = weight + (long)k * CIN * COUT;
#pragma unroll
        for (int e = 0; e < 8; ++e) {
            const int idx = threadIdx.x + e * NTHR;   // 2048 elements
            const int ci  = idx >> 6;                 // coalesced read over cout
            const int co  = idx & 63;
            wt[co * CIN + ci] = wsrc[ci * COUT + co];
        }
    } else if (b == 27) {
        const int bb   = threadIdx.x >> 6;       // cout block 0..3
        const int lane = threadIdx.x & 63;
        const int quad = lane >> 4;
        const int lm   = lane & 15;
        const float* wsrc = weight + (long)13 * CIN * COUT + (quad * 8) * COUT + bb * 16 + lm;
        float f[8];
#pragma unroll
        for (int j = 0; j < 8; ++j) f[j] = wsrc[j * COUT];
        uint4 o;
        o.x = pack_bf2(f[0], f[1]);
        o.y = pack_bf2(f[2], f[3]);
        o.z = pack_bf2(f[4], f[5]);
        o.w = pack_bf2(f[6], f[7]);
        ((uint4*)(ws + WS_W13))[bb * 64 + lane] = o;
    } else {
        float* gs = (float*)(ws + WS_GSTATS);
#pragma unroll
        for (int i = 0; i < 8; ++i) gs[threadIdx.x + i * NTHR] = 0.f;
    }
}

// ---------------------------------------------------------------------------
// K1: dense center-tap GEMM. One wave per 16-voxel tile, contiguous feature
// reads, 4 MFMAs, f32 out rows to ws, center-only BN partials.
// ---------------------------------------------------------------------------
__global__ __launch_bounds__(NTHR) void k_dense(
    const float* __restrict__ feat,    // [NV, CIN] f32
    char*        __restrict__ ws,
    float*       __restrict__ gstats)
{
    const uint4* wf = (const uint4*)(ws + WS_W13);
    float* outf = (float*)(ws + WS_OUTF);

    const int tid  = threadIdx.x;
    const int lane = tid & 63;
    const int quad = lane >> 4;
    const int lm   = lane & 15;
    const int wid  = blockIdx.x * 4 + (tid >> 6);
    const bool have = (wid < NTILES);
    const int v0 = have ? wid * 16 : 0;

    f32x4 ssum = {0.f, 0.f, 0.f, 0.f};
    f32x4 qsum = {0.f, 0.f, 0.f, 0.f};
    f32x4 acc[4] = {{0.f,0.f,0.f,0.f},{0.f,0.f,0.f,0.f},{0.f,0.f,0.f,0.f},{0.f,0.f,0.f,0.f}};

    if (have) {
        const float4* fp = (const float4*)(feat + (long)(v0 + lm) * CIN + quad * 8);
        const u4bf a0 = pack_row(fp[0], fp[1]);
#pragma unroll
        for (int b = 0; b < 4; ++b) {
            u4bf w; w.u = wf[b * 64 + lane];
            acc[b] = __builtin_amdgcn_mfma_f32_16x16x32_bf16(a0.h, w.h, acc[b], 0, 0, 0);
        }
#pragma unroll
        for (int b = 0; b < 4; ++b) {
            const float r0 = acc[b][0], r1 = acc[b][1], r2 = acc[b][2], r3 = acc[b][3];
            outf[(long)(v0 + quad * 4 + 0) * COUT + b * 16 + lm] = r0;
            outf[(long)(v0 + quad * 4 + 1) * COUT + b * 16 + lm] = r1;
            outf[(long)(v0 + quad * 4 + 2) * COUT + b * 16 + lm] = r2;
            outf[(long)(v0 + quad * 4 + 3) * COUT + b * 16 + lm] = r3;
            ssum[b] += r0 + r1 + r2 + r3;
            qsum[b] += r0 * r0 + r1 * r1 + r2 * r2 + r3 * r3;
        }
    }

    // butterfly over quads (channel-aligned partials)
#pragma unroll
    for (int off = 16; off < 64; off <<= 1) {
#pragma unroll
        for (int b = 0; b < 4; ++b) {
            ssum[b] += __shfl_xor(ssum[b], off);
            qsum[b] += __shfl_xor(qsum[b], off);
        }
    }

    __shared__ float ls[4][128];
    const int wv = tid >> 6;
    if (quad == 0) {
#pragma unroll
        for (int b = 0; b < 4; ++b) {
            ls[wv][b * 16 + lm]      = ssum[b];
            ls[wv][64 + b * 16 + lm] = qsum[b];
        }
    }
    __syncthreads();
    if (tid < 128) {
        const float v = ls[0][tid] + ls[1][tid] + ls[2][tid] + ls[3][tid];
        atomicAdd(gstats + (blockIdx.x & (NCOPY - 1)) * 128 + tid, v);
    }
}

// ---------------------------------------------------------------------------
// K2: sparse edges. Coalesced scan of nbr (one k per blockIdx.y, 64
// consecutive voxels per wave); for each valid edge the wave computes
// feat[j] . Wt[k] in f32 (lane = cout channel) and atomicAdds into outf.
// BN stats corrected exactly via the telescoping trick on the returned old.
// ---------------------------------------------------------------------------
__global__ __launch_bounds__(NTHR) void k_sparse(
    const float* __restrict__ feat,    // [NV, CIN] f32
    char*        __restrict__ ws,
    const int*   __restrict__ nbr,     // [27, NV]
    float*       __restrict__ gstats)
{
    const int kp = blockIdx.y;
    const int k  = kp + (kp >= 13);
    const int v  = blockIdx.x * NTHR + (int)threadIdx.x;
    const int lane = threadIdx.x & 63;

    float* outf = (float*)(ws + WS_OUTF);
    const float* wt = (const float*)(ws + WS_WT) + (long)k * COUT * CIN;

    int idx = -1;
    if (v < NV) idx = nbr[(long)k * NV + v];

    unsigned long long mask = __ballot(idx >= 0);
    const bool any = (mask != 0ull);
    float sd = 0.f, qd = 0.f;

    const float4* wl = (const float4*)(wt + lane * CIN);   // lane's cout row

    while (mask) {
        const int l = __ffsll(mask) - 1;
        mask &= mask - 1ull;
        const int j = __shfl(idx, l);      // input voxel
        const int i = __shfl(v, l);        // output voxel

        const float4* fj = (const float4*)(feat + (long)j * CIN);  // broadcast
        float a = 0.f;
#pragma unroll
        for (int e = 0; e < 8; ++e) {
            const float4 f = fj[e];
            const float4 w = wl[e];
            a = fmaf(f.x, w.x, a);
            a = fmaf(f.y, w.y, a);
            a = fmaf(f.z, w.z, a);
            a = fmaf(f.w, w.w, a);
        }
        const float old = atomicAdd(outf + (long)i * COUT + lane, a);
        sd += a;
        qd += a * (a + 2.f * old);   // (old+a)^2 - old^2
    }

    if (any) {
        float* gs = gstats + ((blockIdx.x + blockIdx.y) & (NCOPY - 1)) * 128;
        atomicAdd(gs + lane, sd);
        atomicAdd(gs + 64 + lane, qd);
    }
}

// ---------------------------------------------------------------------------
// K3: finalize stats -> scale/shift; stream f32 conv result, affine+ReLU,
// write f32 d_out. float4 in/out; channel group fixed per thread.
// ---------------------------------------------------------------------------
__global__ __launch_bounds__(NTHR) void k_norm(
    const char*  __restrict__ ws_ro,
    float*       __restrict__ out,
    const float* __restrict__ gstats,
    const float* __restrict__ gamma,
    const float* __restrict__ beta)
{
    __shared__ float sscale[COUT];
    __shared__ float sshift[COUT];
    const int tid = threadIdx.x;
    if (tid < COUT) {
        float s = 0.f, q = 0.f;
#pragma unroll
        for (int cp = 0; cp < NCOPY; ++cp) {
            s += gstats[cp * 128 + tid];
            q += gstats[cp * 128 + 64 + tid];
        }
        const float inv_n = 1.f / (float)NV;
        const float mean = s * inv_n;
        float var = q * inv_n - mean * mean;
        var = fmaxf(var, 0.f);
        const float rstd = rsqrtf(var + EPSF);
        const float sc = gamma[tid] * rstd;
        sscale[tid] = sc;
        sshift[tid] = beta[tid] - mean * sc;
    }
    __syncthreads();

    const int base = blockIdx.x * NTHR + tid;    // float4 chunk id
    const int g    = (base & 15) * 4;            // fixed: STRIDE3 % 16 == 0
    const float4 SC = make_float4(sscale[g], sscale[g+1], sscale[g+2], sscale[g+3]);
    const float4 SH = make_float4(sshift[g], sshift[g+1], sshift[g+2], sshift[g+3]);

    const float4* ib = (const float4*)(ws_ro + WS_OUTF);
    float4* o4 = (float4*)out;

#pragma unroll
    for (int n = 0; n < 8; ++n) {
        const int c = base + n * STRIDE3;
        if (c >= CH4) break;
        float4 v = ib[c];
        v.x = fmaxf(v.x * SC.x + SH.x, 0.f);
        v.y = fmaxf(v.y * SC.y + SH.y, 0.f);
        v.z = fmaxf(v.z * SC.z + SH.z, 0.f);
        v.w = fmaxf(v.w * SC.w + SH.w, 0.f);
        o4[c] = v;
    }
}

// ---------------------------------------------------------------------------
extern "C" void kernel_launch(void* const* d_in, const int* in_sizes, int n_in,
                              void* d_out, int out_size, void* d_ws, size_t ws_size,
                              hipStream_t stream) {
    const float* feat   = (const float*)d_in[0];
    const float* weight = (const float*)d_in[1];
    const float* gamma  = (const float*)d_in[2];
    const float* beta   = (const float*)d_in[3];
    const int*   nbr    = (const int*)d_in[4];
    float* out = (float*)d_out;

    char*  ws     = (char*)d_ws;
    float* gstats = (float*)(ws + WS_GSTATS);

    k_prep<<<29, NTHR, 0, stream>>>(weight, ws);
    k_dense<<<NBLKD, NTHR, 0, stream>>>(feat, ws, gstats);
    k_sparse<<<dim3(VBLK, 26), NTHR, 0, stream>>>(feat, ws, nbr, gstats);
    k_norm<<<NBLK3, NTHR, 0, stream>>>(ws, out, gstats, gamma, beta);
}

// Round 6
// 124.628 us; speedup vs baseline: 2.0437x; 1.3042x over previous
//
#include <hip/hip_runtime.h>

#define NV    150000
#define CIN   32
#define COUT  64
#define EPSF  1e-5f
#define NCOPY 16
#define NTHR  256

#define NTILES (NV / 16)              // 9375 exact
#define NBLK1  ((NTILES + 3) / 4)     // 2344 blocks, 1 tile per wave

// k_norm: chunks of 8 channels (one uint4 of bf16)
#define CH8    (NV * COUT / 8)        // 1,200,000
#define NBLK2  1172
#define STRIDE2 (NBLK2 * NTHR)        // 300,032 (divisible by 8)

// ws layout (bytes):
//   [0, 4096)              uint4 w13frag[4*64]      (center-tap MFMA B-frag, bf16)
//   [4096, 114688)         uint  wtb[27][64][16]    (bf16 Wt pairs: [k][cout][cin/2])
//   [114688, 122880)       float gstats[NCOPY*128]
//   [122880, ...)          ushort out_bf[NV*COUT]   (conv result, bf16)
#define WS_W13    0
#define WS_WTB    4096
#define WS_GSTATS 114688
#define WS_OUTBF  122880

typedef short  bf16x8 __attribute__((ext_vector_type(8)));
typedef float  f32x4  __attribute__((ext_vector_type(4)));

union u4bf { uint4 u; bf16x8 h; };

__device__ __forceinline__ unsigned pack_bf2(float a, float b) {
    union { float f; unsigned u; } ca, cb;
    ca.f = a; cb.f = b;
    const unsigned lo = (ca.u + 0x7FFFu + ((ca.u >> 16) & 1u)) >> 16;
    const unsigned hi = (cb.u + 0x7FFFu + ((cb.u >> 16) & 1u)) & 0xFFFF0000u;
    return lo | hi;
}

__device__ __forceinline__ unsigned short bf16r(float a) {
    union { float f; unsigned u; } c; c.f = a;
    return (unsigned short)((c.u + 0x7FFFu + ((c.u >> 16) & 1u)) >> 16);
}

__device__ __forceinline__ u4bf pack_row(float4 f0, float4 f1) {
    u4bf r;
    r.u.x = pack_bf2(f0.x, f0.y);
    r.u.y = pack_bf2(f0.z, f0.w);
    r.u.z = pack_bf2(f1.x, f1.y);
    r.u.w = pack_bf2(f1.z, f1.w);
    return r;
}

// dot of 8 f32 feats with 8 bf16 weights (one uint4), f32 accumulate
__device__ __forceinline__ float dot8(float4 fa, float4 fb, uint4 w, float c) {
    union { unsigned u; float f; } t;
    t.u = w.x << 16;          c = fmaf(fa.x, t.f, c);
    t.u = w.x & 0xFFFF0000u;  c = fmaf(fa.y, t.f, c);
    t.u = w.y << 16;          c = fmaf(fa.z, t.f, c);
    t.u = w.y & 0xFFFF0000u;  c = fmaf(fa.w, t.f, c);
    t.u = w.z << 16;          c = fmaf(fb.x, t.f, c);
    t.u = w.z & 0xFFFF0000u;  c = fmaf(fb.y, t.f, c);
    t.u = w.w << 16;          c = fmaf(fb.z, t.f, c);
    t.u = w.w & 0xFFFF0000u;  c = fmaf(fb.w, t.f, c);
    return c;
}

// ---------------------------------------------------------------------------
// K0: prep.
//   blocks 0..26 : W[k] f32 [cin][cout] -> bf16 pair table wtb[k][cout][cin/2]
//   block  27    : center-tap (k=13) MFMA B-fragment (bf16, swizzled)
//   block  28    : zero gstats
// ---------------------------------------------------------------------------
__global__ __launch_bounds__(NTHR) void k_prep(
    const float* __restrict__ weight,
    char*        __restrict__ ws)
{
    const int b = blockIdx.x;
    if (b < 27) {
        const int k = b;
        const float* wsrc = weight + (long)k * CIN * COUT;
        unsigned* dst = (unsigned*)(ws + WS_WTB) + k * 1024;
#pragma unroll
        for (int e = 0; e < 4; ++e) {
            const int w  = threadIdx.x * 4 + e;   // 0..1023
            const int co = w >> 4;
            const int ci = (w & 15) * 2;
            dst[w] = pack_bf2(wsrc[ci * COUT + co], wsrc[(ci + 1) * COUT + co]);
        }
    } else if (b == 27) {
        const int bb   = threadIdx.x >> 6;       // cout block 0..3
        const int lane = threadIdx.x & 63;
        const int quad = lane >> 4;
        const int lm   = lane & 15;
        const float* wsrc = weight + (long)13 * CIN * COUT + (quad * 8) * COUT + bb * 16 + lm;
        float f[8];
#pragma unroll
        for (int j = 0; j < 8; ++j) f[j] = wsrc[j * COUT];
        uint4 o;
        o.x = pack_bf2(f[0], f[1]);
        o.y = pack_bf2(f[2], f[3]);
        o.z = pack_bf2(f[4], f[5]);
        o.w = pack_bf2(f[6], f[7]);
        ((uint4*)(ws + WS_W13))[bb * 64 + lane] = o;
    } else {
        float* gs = (float*)(ws + WS_GSTATS);
#pragma unroll
        for (int i = 0; i < 8; ++i) gs[threadIdx.x + i * NTHR] = 0.f;
    }
}

// ---------------------------------------------------------------------------
// K1: one wave per 16-voxel tile. Dense center tap via MFMA; sparse neighbor
// taps via per-EDGE drain (~3.7 edges/tile): broadcast feat row, bf16 W-row
// per lane (lane = cout), f32 dot, shfl-redistribute into the MFMA-layout
// accumulator. No atomics to outf; bf16 out + 16-copy gstats partials.
// ---------------------------------------------------------------------------
__global__ __launch_bounds__(NTHR) void k_conv(
    const float* __restrict__ feat,    // [NV, CIN] f32
    char*        __restrict__ ws,
    const int*   __restrict__ nbr,     // [27, NV]
    float*       __restrict__ gstats)
{
    const uint4* wf  = (const uint4*)(ws + WS_W13);
    const uint4* wtb = (const uint4*)(ws + WS_WTB);   // [k*64+cout]*4 uint4s
    unsigned short* ob = (unsigned short*)(ws + WS_OUTBF);

    const int tid  = threadIdx.x;
    const int lane = tid & 63;
    const int quad = lane >> 4;
    const int lm   = lane & 15;
    const int wid  = blockIdx.x * 4 + (tid >> 6);   // tile id
    const bool have = (wid < NTILES);
    const int v0 = have ? wid * 16 : 0;

    f32x4 ssum = {0.f, 0.f, 0.f, 0.f};
    f32x4 qsum = {0.f, 0.f, 0.f, 0.f};
    f32x4 acc[4] = {{0.f,0.f,0.f,0.f},{0.f,0.f,0.f,0.f},{0.f,0.f,0.f,0.f},{0.f,0.f,0.f,0.f}};

    // ---- 1) scan loads: 26 taps x 16 voxels = 416 items ----
    int sidx[7];
#pragma unroll
    for (int it = 0; it < 7; ++it) {
        const int item = lane + it * 64;
        int idx = -1;
        if (have && item < 416) {
            const int kp = item >> 4;
            const int k  = kp + (kp >= 13);
            idx = nbr[(long)k * NV + v0 + (item & 15)];
        }
        sidx[it] = idx;
    }

    // ---- 2) dense center tap MFMA ----
    if (have) {
        const float4* fp = (const float4*)(feat + (long)(v0 + lm) * CIN + quad * 8);
        const u4bf a0 = pack_row(fp[0], fp[1]);
#pragma unroll
        for (int b = 0; b < 4; ++b) {
            u4bf w; w.u = wf[b * 64 + lane];
            acc[b] = __builtin_amdgcn_mfma_f32_16x16x32_bf16(a0.h, w.h, acc[b], 0, 0, 0);
        }
    }

    // ---- 3) per-edge drain (wave-uniform scalar walk of 7 ballot masks) ----
#pragma unroll
    for (int it = 0; it < 7; ++it) {
        unsigned long long m = __ballot(sidx[it] >= 0);
        while (m) {
            const int l = __ffsll(m) - 1;
            m &= m - 1ull;
            const int item = it * 64 + l;          // uniform
            const int kp   = item >> 4;
            const int k    = kp + (kp >= 13);
            const int slot = item & 15;            // uniform
            const int j    = __shfl(sidx[it], l);  // input voxel (uniform value)

            // feat row broadcast (8 float4, same addr across lanes -> bcast)
            const float4* fj = (const float4*)(feat + (long)j * CIN);
            float4 f0 = fj[0], f1 = fj[1], f2 = fj[2], f3 = fj[3];
            float4 f4 = fj[4], f5 = fj[5], f6 = fj[6], f7 = fj[7];

            // lane's cout-row of W[k] (32 bf16 = 4 uint4, 64B/lane, L2-hot)
            const uint4* wr = wtb + ((k * 64 + lane) << 2);
            const uint4 wA = wr[0], wB = wr[1], wC = wr[2], wD = wr[3];

            float c = 0.f;
            c = dot8(f0, f1, wA, c);
            c = dot8(f2, f3, wB, c);
            c = dot8(f4, f5, wC, c);
            c = dot8(f6, f7, wD, c);

            // redistribute: target row = slot = sq*4 + sr; cols spread b*16+lm
            const float vb0 = __shfl(c, 0 * 16 + lm);
            const float vb1 = __shfl(c, 1 * 16 + lm);
            const float vb2 = __shfl(c, 2 * 16 + lm);
            const float vb3 = __shfl(c, 3 * 16 + lm);
            const int sq = slot >> 2;
            switch (slot & 3) {                    // uniform branch, static idx
                case 0: if (quad == sq) { acc[0][0]+=vb0; acc[1][0]+=vb1; acc[2][0]+=vb2; acc[3][0]+=vb3; } break;
                case 1: if (quad == sq) { acc[0][1]+=vb0; acc[1][1]+=vb1; acc[2][1]+=vb2; acc[3][1]+=vb3; } break;
                case 2: if (quad == sq) { acc[0][2]+=vb0; acc[1][2]+=vb1; acc[2][2]+=vb2; acc[3][2]+=vb3; } break;
                default: if (quad == sq) { acc[0][3]+=vb0; acc[1][3]+=vb1; acc[2][3]+=vb2; acc[3][3]+=vb3; } break;
            }
        }
    }

    // ---- 4) store bf16 rows + BN partials from f32 values ----
    if (have) {
#pragma unroll
        for (int b = 0; b < 4; ++b) {
            const float r0 = acc[b][0], r1 = acc[b][1], r2 = acc[b][2], r3 = acc[b][3];
            ob[(long)(v0 + quad * 4 + 0) * COUT + b * 16 + lm] = bf16r(r0);
            ob[(long)(v0 + quad * 4 + 1) * COUT + b * 16 + lm] = bf16r(r1);
            ob[(long)(v0 + quad * 4 + 2) * COUT + b * 16 + lm] = bf16r(r2);
            ob[(long)(v0 + quad * 4 + 3) * COUT + b * 16 + lm] = bf16r(r3);
            ssum[b] += r0 + r1 + r2 + r3;
            qsum[b] += r0 * r0 + r1 * r1 + r2 * r2 + r3 * r3;
        }
    }

    // ---- butterfly over quads ----
#pragma unroll
    for (int off = 16; off < 64; off <<= 1) {
#pragma unroll
        for (int b = 0; b < 4; ++b) {
            ssum[b] += __shfl_xor(ssum[b], off);
            qsum[b] += __shfl_xor(qsum[b], off);
        }
    }

    __shared__ float ls[4][128];
    const int wv = tid >> 6;
    if (quad == 0) {
#pragma unroll
        for (int b = 0; b < 4; ++b) {
            ls[wv][b * 16 + lm]      = ssum[b];
            ls[wv][64 + b * 16 + lm] = qsum[b];
        }
    }
    __syncthreads();
    if (tid < 128) {
        const float v = ls[0][tid] + ls[1][tid] + ls[2][tid] + ls[3][tid];
        atomicAdd(gstats + (blockIdx.x & (NCOPY - 1)) * 128 + tid, v);
    }
}

// ---------------------------------------------------------------------------
// K2: stripe reduce -> scale/shift, then read bf16 conv result, apply
// affine + ReLU, write f32 d_out. (Proven R0 kernel.)
// ---------------------------------------------------------------------------
__global__ __launch_bounds__(NTHR) void k_norm(
    const char*  __restrict__ ws_ro,
    float*       __restrict__ out,
    const float* __restrict__ gstats,
    const float* __restrict__ gamma,
    const float* __restrict__ beta)
{
    __shared__ float sscale[COUT];
    __shared__ float sshift[COUT];
    const int tid = threadIdx.x;
    if (tid < COUT) {
        float s = 0.f, q = 0.f;
#pragma unroll
        for (int cp = 0; cp < NCOPY; ++cp) {
            s += gstats[cp * 128 + tid];
            q += gstats[cp * 128 + 64 + tid];
        }
        const float inv_n = 1.f / (float)NV;
        const float mean = s * inv_n;
        float var = q * inv_n - mean * mean;
        var = fmaxf(var, 0.f);
        const float rstd = rsqrtf(var + EPSF);
        const float sc = gamma[tid] * rstd;
        sscale[tid] = sc;
        sshift[tid] = beta[tid] - mean * sc;
    }
    __syncthreads();

    const int  base = blockIdx.x * NTHR + tid;     // chunk id (8 channels)
    const int  g8   = (base & 7) * 8;              // fixed: STRIDE2 % 8 == 0
    const float4 SC0 = make_float4(sscale[g8],   sscale[g8+1], sscale[g8+2], sscale[g8+3]);
    const float4 SC1 = make_float4(sscale[g8+4], sscale[g8+5], sscale[g8+6], sscale[g8+7]);
    const float4 SH0 = make_float4(sshift[g8],   sshift[g8+1], sshift[g8+2], sshift[g8+3]);
    const float4 SH1 = make_float4(sshift[g8+4], sshift[g8+5], sshift[g8+6], sshift[g8+7]);

    const uint4* ib = (const uint4*)(ws_ro + WS_OUTBF);
    float4* o4 = (float4*)out;

#pragma unroll
    for (int n = 0; n < 4; ++n) {
        const int c = base + n * STRIDE2;
        if (n == 3 && c >= CH8) break;
        const uint4 u = ib[c];
        union { unsigned u; float f; } t;
        float4 v0, v1;
        t.u = u.x << 16;          v0.x = t.f;
        t.u = u.x & 0xFFFF0000u;  v0.y = t.f;
        t.u = u.y << 16;          v0.z = t.f;
        t.u = u.y & 0xFFFF0000u;  v0.w = t.f;
        t.u = u.z << 16;          v1.x = t.f;
        t.u = u.z & 0xFFFF0000u;  v1.y = t.f;
        t.u = u.w << 16;          v1.z = t.f;
        t.u = u.w & 0xFFFF0000u;  v1.w = t.f;

        v0.x = fmaxf(v0.x * SC0.x + SH0.x, 0.f);
        v0.y = fmaxf(v0.y * SC0.y + SH0.y, 0.f);
        v0.z = fmaxf(v0.z * SC0.z + SH0.z, 0.f);
        v0.w = fmaxf(v0.w * SC0.w + SH0.w, 0.f);
        v1.x = fmaxf(v1.x * SC1.x + SH1.x, 0.f);
        v1.y = fmaxf(v1.y * SC1.y + SH1.y, 0.f);
        v1.z = fmaxf(v1.z * SC1.z + SH1.z, 0.f);
        v1.w = fmaxf(v1.w * SC1.w + SH1.w, 0.f);

        o4[(long)c * 2]     = v0;
        o4[(long)c * 2 + 1] = v1;
    }
}

// ---------------------------------------------------------------------------
extern "C" void kernel_launch(void* const* d_in, const int* in_sizes, int n_in,
                              void* d_out, int out_size, void* d_ws, size_t ws_size,
                              hipStream_t stream) {
    const float* feat   = (const float*)d_in[0];
    const float* weight = (const float*)d_in[1];
    const float* gamma  = (const float*)d_in[2];
    const float* beta   = (const float*)d_in[3];
    const int*   nbr    = (const int*)d_in[4];
    float* out = (float*)d_out;

    char*  ws     = (char*)d_ws;
    float* gstats = (float*)(ws + WS_GSTATS);

    k_prep<<<29, NTHR, 0, stream>>>(weight, ws);
    k_conv<<<NBLK1, NTHR, 0, stream>>>(feat, ws, nbr, gstats);
    k_norm<<<NBLK2, NTHR, 0, stream>>>(ws, out, gstats, gamma, beta);
}

// Round 7
// 116.951 us; speedup vs baseline: 2.1779x; 1.0656x over previous
//
#include <hip/hip_runtime.h>

#define NV    150000
#define CIN   32
#define COUT  64
#define EPSF  1e-5f
#define NCOPY 16

#define NTHR   256
#define NTILES (NV / 16)              // 9375 exact
#define NBLK1  ((NTILES + 3) / 4)     // 2344 blocks, 1 tile per wave

// k_norm: chunks of 8 channels (one uint4 of bf16)
#define CH8    (NV * COUT / 8)        // 1,200,000
#define NBLK2  1172
#define STRIDE2 (NBLK2 * NTHR)        // 300,032 (divisible by 8)

// ws layout (bytes):
//   [0, 110592)             ushort wfrag[27*4*64*8]  (B-fragment swizzled)
//   [110592, 118784)        float  gstats[NCOPY*128]
//   [118784, 19318784)      ushort out_bf[NV*COUT]   (conv result, bf16)
#define WS_WFRAG  0
#define WS_GSTATS 110592
#define WS_OUTBF  118784

typedef short  bf16x8 __attribute__((ext_vector_type(8)));
typedef float  f32x4  __attribute__((ext_vector_type(4)));

union u4bf { uint4 u; bf16x8 h; };

__device__ __forceinline__ unsigned pack_bf2(float a, float b) {
    union { float f; unsigned u; } ca, cb;
    ca.f = a; cb.f = b;
    const unsigned lo = (ca.u + 0x7FFFu + ((ca.u >> 16) & 1u)) >> 16;
    const unsigned hi = (cb.u + 0x7FFFu + ((cb.u >> 16) & 1u)) & 0xFFFF0000u;
    return lo | hi;
}

__device__ __forceinline__ unsigned short bf16r(float a) {
    union { float f; unsigned u; } c; c.f = a;
    return (unsigned short)((c.u + 0x7FFFu + ((c.u >> 16) & 1u)) >> 16);
}

__device__ __forceinline__ u4bf pack_row(float4 f0, float4 f1) {
    u4bf r;
    r.u.x = pack_bf2(f0.x, f0.y);
    r.u.y = pack_bf2(f0.z, f0.w);
    r.u.z = pack_bf2(f1.x, f1.y);
    r.u.w = pack_bf2(f1.z, f1.w);
    return r;
}

// kp is wave-uniform; static-index selection of the scan register (rule #20)
__device__ __forceinline__ int sel_raw(const int (&sidx)[7], int kp) {
    switch (kp >> 2) {
        case 0: return sidx[0]; case 1: return sidx[1];
        case 2: return sidx[2]; case 3: return sidx[3];
        case 4: return sidx[4]; case 5: return sidx[5];
        default: return sidx[6];
    }
}

// ---------------------------------------------------------------------------
// K0: prep — weights->B-fragment-swizzled bf16 (27 blocks) + gstats zero (1).
// ---------------------------------------------------------------------------
__global__ __launch_bounds__(NTHR) void k_prep(
    const float* __restrict__ weight,
    char*        __restrict__ ws)
{
    const int b = blockIdx.x;
    if (b < 27) {
        const int k    = b;
        const int bb   = threadIdx.x >> 6;       // cout block 0..3
        const int lane = threadIdx.x & 63;
        const int quad = lane >> 4;
        const int lm   = lane & 15;
        // entry holds weight[k][quad*8+j][bb*16+lm], j=0..7
        const float* wsrc = weight + (long)k * CIN * COUT + (quad * 8) * COUT + bb * 16 + lm;
        float f[8];
#pragma unroll
        for (int j = 0; j < 8; ++j) f[j] = wsrc[j * COUT];
        uint4 o;
        o.x = pack_bf2(f[0], f[1]);
        o.y = pack_bf2(f[2], f[3]);
        o.z = pack_bf2(f[4], f[5]);
        o.w = pack_bf2(f[6], f[7]);
        ((uint4*)(ws + WS_WFRAG))[(k * 4 + bb) * 64 + lane] = o;
    } else {
        float* gs = (float*)(ws + WS_GSTATS);
#pragma unroll
        for (int i = 0; i < 8; ++i) gs[threadIdx.x + i * NTHR] = 0.f;
    }
}

// ---------------------------------------------------------------------------
// K1: one wave per 16-voxel tile (R0 structure). New: 4-tap issue window —
// after the ballots, gathers for the first FOUR active taps are issued
// together and their latency is overlapped with the center-tap pack+MFMA.
// Leftover taps (26% of tiles) drain with the proven 2-tap loop.
// ---------------------------------------------------------------------------
__global__ __launch_bounds__(NTHR) void k_conv(
    const float* __restrict__ feat,    // [NV, CIN] f32
    char*        __restrict__ ws,      // wfrag + gstats + out_bf
    const int*   __restrict__ nbr,     // [27, NV]
    float*       __restrict__ gstats)
{
    const uint4* wf = (const uint4*)(ws + WS_WFRAG);    // wfrag[(k*4+b)*64+lane]
    unsigned short* ob = (unsigned short*)(ws + WS_OUTBF);

    const int tid  = threadIdx.x;
    const int lane = tid & 63;
    const int quad = lane >> 4;
    const int lm   = lane & 15;
    const int wid  = blockIdx.x * 4 + (tid >> 6);   // == tile id

    f32x4 ssum = {0.f, 0.f, 0.f, 0.f};
    f32x4 qsum = {0.f, 0.f, 0.f, 0.f};
    f32x4 acc[4] = {{0.f,0.f,0.f,0.f},{0.f,0.f,0.f,0.f},{0.f,0.f,0.f,0.f},{0.f,0.f,0.f,0.f}};

    const bool have_tile = (wid < NTILES);
    const int v0 = have_tile ? wid * 16 : 0;

    if (have_tile) {
        // ---- 1) scan loads: 26 taps x 16 voxels = 416 items ----
        int sidx[7];
#pragma unroll
        for (int it = 0; it < 7; ++it) {
            const int item = lane + it * 64;
            int idx = -1;
            if (item < 416) {
                const int kp = item >> 4;
                const int k  = kp + (kp >= 13);
                idx = nbr[(long)k * NV + v0 + (item & 15)];
            }
            sidx[it] = idx;
        }

        // ---- 2) issue center-tap feature load early ----
        const float4* fpc = (const float4*)(feat + (long)(v0 + lm) * CIN + quad * 8);
        const float4 c0 = fpc[0], c1 = fpc[1];

        // ---- 3) ballots -> wave-uniform 26-bit active-k mask ----
        unsigned int kmask = 0u;
#pragma unroll
        for (int it = 0; it < 7; ++it) {
            const unsigned long long m = __ballot(sidx[it] >= 0);
            kmask |= ((m & 0xFFFFull)         ? 1u : 0u) << (it * 4 + 0);
            kmask |= (((m >> 16) & 0xFFFFull) ? 1u : 0u) << (it * 4 + 1);
            kmask |= (((m >> 32) & 0xFFFFull) ? 1u : 0u) << (it * 4 + 2);
            kmask |= ((m >> 48)               ? 1u : 0u) << (it * 4 + 3);
        }

        // ---- 4) extract up to 4 taps, issue ALL their gathers now ----
        int kpA = -1, kpB = -1, kpC = -1, kpD = -1;
        if (kmask) { kpA = __ffs(kmask) - 1; kmask &= kmask - 1u; }
        if (kmask) { kpB = __ffs(kmask) - 1; kmask &= kmask - 1u; }
        if (kmask) { kpC = __ffs(kmask) - 1; kmask &= kmask - 1u; }
        if (kmask) { kpD = __ffs(kmask) - 1; kmask &= kmask - 1u; }

        int idxA = -1, idxB = -1, idxC = -1, idxD = -1;
        if (kpA >= 0) idxA = __shfl(sel_raw(sidx, kpA), ((kpA & 3) << 4) | lm);
        if (kpB >= 0) idxB = __shfl(sel_raw(sidx, kpB), ((kpB & 3) << 4) | lm);
        if (kpC >= 0) idxC = __shfl(sel_raw(sidx, kpC), ((kpC & 3) << 4) | lm);
        if (kpD >= 0) idxD = __shfl(sel_raw(sidx, kpD), ((kpD & 3) << 4) | lm);

        float4 rA0 = {0,0,0,0}, rA1 = {0,0,0,0}, rB0 = {0,0,0,0}, rB1 = {0,0,0,0};
        float4 rC0 = {0,0,0,0}, rC1 = {0,0,0,0}, rD0 = {0,0,0,0}, rD1 = {0,0,0,0};
        if (kpA >= 0) { const float4* g = (const float4*)(feat + (long)(idxA < 0 ? 0 : idxA) * CIN + quad * 8); rA0 = g[0]; rA1 = g[1]; }
        if (kpB >= 0) { const float4* g = (const float4*)(feat + (long)(idxB < 0 ? 0 : idxB) * CIN + quad * 8); rB0 = g[0]; rB1 = g[1]; }
        if (kpC >= 0) { const float4* g = (const float4*)(feat + (long)(idxC < 0 ? 0 : idxC) * CIN + quad * 8); rC0 = g[0]; rC1 = g[1]; }
        if (kpD >= 0) { const float4* g = (const float4*)(feat + (long)(idxD < 0 ? 0 : idxD) * CIN + quad * 8); rD0 = g[0]; rD1 = g[1]; }

        // ---- 5) center tap compute (overlaps window gather latency) ----
        {
            const u4bf a0 = pack_row(c0, c1);
#pragma unroll
            for (int b = 0; b < 4; ++b) {
                u4bf w; w.u = wf[(13 * 4 + b) * 64 + lane];
                acc[b] = __builtin_amdgcn_mfma_f32_16x16x32_bf16(a0.h, w.h, acc[b], 0, 0, 0);
            }
        }

        // ---- 6) window MFMAs (pairs A,B then C,D) ----
        if (kpA >= 0) {
            u4bf aA = pack_row(rA0, rA1);
            u4bf aB = pack_row(rB0, rB1);
            if (idxA < 0) aA.u = make_uint4(0u, 0u, 0u, 0u);
            if (idxB < 0) aB.u = make_uint4(0u, 0u, 0u, 0u);
            const int kA = kpA + (kpA >= 13);
            const int kB = (kpB >= 0) ? (kpB + (kpB >= 13)) : kA;
#pragma unroll
            for (int b = 0; b < 4; ++b) {
                u4bf wA, wB;
                wA.u = wf[(kA * 4 + b) * 64 + lane];
                wB.u = wf[(kB * 4 + b) * 64 + lane];
                acc[b] = __builtin_amdgcn_mfma_f32_16x16x32_bf16(aA.h, wA.h, acc[b], 0, 0, 0);
                acc[b] = __builtin_amdgcn_mfma_f32_16x16x32_bf16(aB.h, wB.h, acc[b], 0, 0, 0);
            }
        }
        if (kpC >= 0) {
            u4bf aC = pack_row(rC0, rC1);
            u4bf aD = pack_row(rD0, rD1);
            if (idxC < 0) aC.u = make_uint4(0u, 0u, 0u, 0u);
            if (idxD < 0) aD.u = make_uint4(0u, 0u, 0u, 0u);
            const int kC = kpC + (kpC >= 13);
            const int kD = (kpD >= 0) ? (kpD + (kpD >= 13)) : kC;
#pragma unroll
            for (int b = 0; b < 4; ++b) {
                u4bf wC, wD;
                wC.u = wf[(kC * 4 + b) * 64 + lane];
                wD.u = wf[(kD * 4 + b) * 64 + lane];
                acc[b] = __builtin_amdgcn_mfma_f32_16x16x32_bf16(aC.h, wC.h, acc[b], 0, 0, 0);
                acc[b] = __builtin_amdgcn_mfma_f32_16x16x32_bf16(aD.h, wD.h, acc[b], 0, 0, 0);
            }
        }

        // ---- 7) leftover drain: proven 2-tap loop (26% of tiles) ----
        while (kmask) {
            const int kpE = __ffs(kmask) - 1;
            kmask &= kmask - 1u;
            int kpF = -1;
            if (kmask) { kpF = __ffs(kmask) - 1; kmask &= kmask - 1u; }
            const int kE = kpE + (kpE >= 13);
            const int kF = (kpF >= 0) ? (kpF + (kpF >= 13)) : kE;

            const int kpF2 = (kpF >= 0) ? kpF : kpE;
            const int idxE = __shfl(sel_raw(sidx, kpE),  ((kpE  & 3) << 4) | lm);
            int idxF = __shfl(sel_raw(sidx, kpF2), ((kpF2 & 3) << 4) | lm);
            if (kpF < 0) idxF = -1;

            const float4* fpE = (const float4*)(feat + (long)(idxE < 0 ? 0 : idxE) * CIN + quad * 8);
            const float4* fpF = (const float4*)(feat + (long)(idxF < 0 ? 0 : idxF) * CIN + quad * 8);
            u4bf aE = pack_row(fpE[0], fpE[1]);
            u4bf aF = pack_row(fpF[0], fpF[1]);
            if (idxE < 0) aE.u = make_uint4(0u, 0u, 0u, 0u);
            if (idxF < 0) aF.u = make_uint4(0u, 0u, 0u, 0u);

#pragma unroll
            for (int b = 0; b < 4; ++b) {
                u4bf wE, wF;
                wE.u = wf[(kE * 4 + b) * 64 + lane];
                wF.u = wf[(kF * 4 + b) * 64 + lane];
                acc[b] = __builtin_amdgcn_mfma_f32_16x16x32_bf16(aE.h, wE.h, acc[b], 0, 0, 0);
                acc[b] = __builtin_amdgcn_mfma_f32_16x16x32_bf16(aF.h, wF.h, acc[b], 0, 0, 0);
            }
        }

        // ---- 8) store bf16 rows + BN partials from f32 values ----
#pragma unroll
        for (int b = 0; b < 4; ++b) {
            const float r0 = acc[b][0], r1 = acc[b][1], r2 = acc[b][2], r3 = acc[b][3];
            ob[(long)(v0 + quad * 4 + 0) * COUT + b * 16 + lm] = bf16r(r0);
            ob[(long)(v0 + quad * 4 + 1) * COUT + b * 16 + lm] = bf16r(r1);
            ob[(long)(v0 + quad * 4 + 2) * COUT + b * 16 + lm] = bf16r(r2);
            ob[(long)(v0 + quad * 4 + 3) * COUT + b * 16 + lm] = bf16r(r3);
            ssum[b] += r0 + r1 + r2 + r3;
            qsum[b] += r0 * r0 + r1 * r1 + r2 * r2 + r3 * r3;
        }
    }

    // ---- butterfly over quads ----
#pragma unroll
    for (int off = 16; off < 64; off <<= 1) {
#pragma unroll
        for (int b = 0; b < 4; ++b) {
            ssum[b] += __shfl_xor(ssum[b], off);
            qsum[b] += __shfl_xor(qsum[b], off);
        }
    }

    __shared__ float ls[4][128];
    const int wv = tid >> 6;
    if (quad == 0) {
#pragma unroll
        for (int b = 0; b < 4; ++b) {
            ls[wv][b * 16 + lm]      = ssum[b];
            ls[wv][64 + b * 16 + lm] = qsum[b];
        }
    }
    __syncthreads();
    if (tid < 128) {
        const float v = ls[0][tid] + ls[1][tid] + ls[2][tid] + ls[3][tid];
        atomicAdd(gstats + (blockIdx.x & (NCOPY - 1)) * 128 + tid, v);
    }
}

// ---------------------------------------------------------------------------
// K2: stripe reduce -> scale/shift, then read bf16 conv result, apply
// affine + ReLU, write f32 d_out. (Proven R0 kernel.)
// ---------------------------------------------------------------------------
__global__ __launch_bounds__(NTHR) void k_norm(
    const char*  __restrict__ ws_ro,   // out_bf
    float*       __restrict__ out,
    const float* __restrict__ gstats,
    const float* __restrict__ gamma,
    const float* __restrict__ beta)
{
    __shared__ float sscale[COUT];
    __shared__ float sshift[COUT];
    const int tid = threadIdx.x;
    if (tid < COUT) {
        float s = 0.f, q = 0.f;
#pragma unroll
        for (int cp = 0; cp < NCOPY; ++cp) {
            s += gstats[cp * 128 + tid];
            q += gstats[cp * 128 + 64 + tid];
        }
        const float inv_n = 1.f / (float)NV;
        const float mean = s * inv_n;
        float var = q * inv_n - mean * mean;
        var = fmaxf(var, 0.f);
        const float rstd = rsqrtf(var + EPSF);
        const float sc = gamma[tid] * rstd;
        sscale[tid] = sc;
        sshift[tid] = beta[tid] - mean * sc;
    }
    __syncthreads();

    const int  base = blockIdx.x * NTHR + tid;     // chunk id (8 channels)
    const int  g8   = (base & 7) * 8;              // fixed: STRIDE2 % 8 == 0
    const float4 SC0 = make_float4(sscale[g8],   sscale[g8+1], sscale[g8+2], sscale[g8+3]);
    const float4 SC1 = make_float4(sscale[g8+4], sscale[g8+5], sscale[g8+6], sscale[g8+7]);
    const float4 SH0 = make_float4(sshift[g8],   sshift[g8+1], sshift[g8+2], sshift[g8+3]);
    const float4 SH1 = make_float4(sshift[g8+4], sshift[g8+5], sshift[g8+6], sshift[g8+7]);

    const uint4* ib = (const uint4*)(ws_ro + WS_OUTBF);
    float4* o4 = (float4*)out;

#pragma unroll
    for (int n = 0; n < 4; ++n) {
        const int c = base + n * STRIDE2;
        if (n == 3 && c >= CH8) break;
        const uint4 u = ib[c];
        union { unsigned u; float f; } t;
        float4 v0, v1;
        t.u = u.x << 16;          v0.x = t.f;
        t.u = u.x & 0xFFFF0000u;  v0.y = t.f;
        t.u = u.y << 16;          v0.z = t.f;
        t.u = u.y & 0xFFFF0000u;  v0.w = t.f;
        t.u = u.z << 16;          v1.x = t.f;
        t.u = u.z & 0xFFFF0000u;  v1.y = t.f;
        t.u = u.w << 16;          v1.z = t.f;
        t.u = u.w & 0xFFFF0000u;  v1.w = t.f;

        v0.x = fmaxf(v0.x * SC0.x + SH0.x, 0.f);
        v0.y = fmaxf(v0.y * SC0.y + SH0.y, 0.f);
        v0.z = fmaxf(v0.z * SC0.z + SH0.z, 0.f);
        v0.w = fmaxf(v0.w * SC0.w + SH0.w, 0.f);
        v1.x = fmaxf(v1.x * SC1.x + SH1.x, 0.f);
        v1.y = fmaxf(v1.y * SC1.y + SH1.y, 0.f);
        v1.z = fmaxf(v1.z * SC1.z + SH1.z, 0.f);
        v1.w = fmaxf(v1.w * SC1.w + SH1.w, 0.f);

        o4[(long)c * 2]     = v0;
        o4[(long)c * 2 + 1] = v1;
    }
}

// ---------------------------------------------------------------------------
extern "C" void kernel_launch(void* const* d_in, const int* in_sizes, int n_in,
                              void* d_out, int out_size, void* d_ws, size_t ws_size,
                              hipStream_t stream) {
    const float* feat   = (const float*)d_in[0];
    const float* weight = (const float*)d_in[1];
    const float* gamma  = (const float*)d_in[2];
    const float* beta   = (const float*)d_in[3];
    const int*   nbr    = (const int*)d_in[4];
    float* out = (float*)d_out;

    char*  ws     = (char*)d_ws;
    float* gstats = (float*)(ws + WS_GSTATS);

    k_prep<<<28, NTHR, 0, stream>>>(weight, ws);
    k_conv<<<NBLK1, NTHR, 0, stream>>>(feat, ws, nbr, gstats);
    k_norm<<<NBLK2, NTHR, 0, stream>>>(ws, out, gstats, gamma, beta);
}